// Round 1
// baseline (398.012 us; speedup 1.0000x reference)
//
#include <hip/hip_runtime.h>
#include <hip/hip_bf16.h>

#define H_   32
#define KVH_ 8
#define D_   128
#define DV_  128
#define SEQ_ 1024
#define QKD  (H_*D_)     // 4096 floats per token row of Q
#define KVD  (KVH_*D_)   // 1024 floats per token row of K/V
#define SCALE_ 0.08838834764831845f
#define LOG2E_ 1.4426950408889634f

typedef __attribute__((ext_vector_type(8))) short bf16x8;
typedef __attribute__((ext_vector_type(4))) float f32x4;
typedef __attribute__((ext_vector_type(4))) unsigned int u32x4;

#if __has_builtin(__builtin_amdgcn_exp2f)
#define EXP2F(x) __builtin_amdgcn_exp2f(x)
#else
#define EXP2F(x) exp2f(x)
#endif

__device__ __forceinline__ unsigned short f2b(float x) {
    __hip_bfloat16 b = __float2bfloat16(x);
    return __builtin_bit_cast(unsigned short, b);
}

// V^T LDS tile: [dv=128][row stride 40 halfs = 80B] (32 k-cols used, +8 pad)
// P per-wave LDS tile: [q=16][row stride 40 halfs]   (32 k-cols used)
#define VT_STR 40
#define PW_STR 40

__global__ __launch_bounds__(256, 2)
void attn_fwd(const float* __restrict__ Q, const float* __restrict__ K,
              const float* __restrict__ V, float* __restrict__ O) {
    __shared__ __align__(16) unsigned short VT[DV_ * VT_STR];
    __shared__ __align__(16) unsigned short PW[4][16 * PW_STR];

    // XCD-bijective swizzle: 2048 blocks, 8 XCDs -> contiguous 256-chunk per XCD
    const int bid = ((int)blockIdx.x & 7) * 256 + ((int)blockIdx.x >> 3);
    const int qt  = bid & 15;          // q-tile within sequence (64 rows each)
    const int h   = (bid >> 4) & 31;   // query head
    const int b   = bid >> 9;          // batch
    const int kvh = h >> 2;            // GQA: group size 4

    const int tid = threadIdx.x;
    const int w   = tid >> 6;          // wave id 0..3
    const int l   = tid & 63;
    const int lo  = l & 15;
    const int g   = l >> 4;

    const int qw0 = qt * 64 + w * 16;  // wave's first q row (within sequence)

    const float* Qb = Q + ((size_t)(b * SEQ_ + qw0 + lo)) * QKD + h * D_;
    const float* Kb = K + ((size_t)(b * SEQ_)) * KVD + kvh * D_;
    const float* Vb = V + ((size_t)(b * SEQ_)) * KVD + kvh * DV_;

    // ---- Q fragments (A-operand): row = lo, d = 32c + 8g + e ----
    bf16x8 qf[4];
#pragma unroll
    for (int c = 0; c < 4; ++c) {
        const float* p = Qb + c * 32 + g * 8;
        float4 x0 = *(const float4*)(p);
        float4 x1 = *(const float4*)(p + 4);
        bf16x8 f;
        f[0] = f2b(x0.x); f[1] = f2b(x0.y); f[2] = f2b(x0.z); f[3] = f2b(x0.w);
        f[4] = f2b(x1.x); f[5] = f2b(x1.y); f[6] = f2b(x1.z); f[7] = f2b(x1.w);
        qf[c] = f;
    }

    float m_[4], lsum[4];
    f32x4 o_[8];
#pragma unroll
    for (int i = 0; i < 4; ++i) { m_[i] = -INFINITY; lsum[i] = 0.f; }
#pragma unroll
    for (int db = 0; db < 8; ++db) o_[db] = (f32x4){0.f, 0.f, 0.f, 0.f};

    const int ntiles = 2 * qt + 2;            // block processes k-tiles [0, ntiles)
    const int jmaxw  = (qw0 + 15) >> 5;       // last tile this wave computes (incl.)

    // V staging mapping: thread -> (dv, k-half)
    const int sdv = tid & 127;
    const int skh = tid >> 7;                 // 0 or 1

    for (int j = 0; j < ntiles; ++j) {
        __syncthreads();  // previous tile's V reads done before overwrite
        // ---- stage V^T tile: columns gathered from global, b128 LDS writes ----
#pragma unroll
        for (int p = 0; p < 2; ++p) {
            const int kkl = skh * 16 + p * 8;                 // local k col 0..31
            const float* vp = Vb + ((size_t)(j * 32 + kkl)) * KVD + sdv;
            unsigned int pk[4];
#pragma unroll
            for (int x = 0; x < 4; ++x) {
                float a = vp[(size_t)(2 * x) * KVD];
                float c2 = vp[(size_t)(2 * x + 1) * KVD];
                pk[x] = (unsigned)f2b(a) | ((unsigned)f2b(c2) << 16);
            }
            *(u32x4*)(&VT[sdv * VT_STR + kkl]) = (u32x4){pk[0], pk[1], pk[2], pk[3]};
        }
        __syncthreads();

        if (j > jmaxw) continue;   // fully-masked tile for this wave

        const int k0 = j * 32;

        // ---- S = Q K^T : two 16x16 accumulators (k-blocks), 4 d-chunks ----
        f32x4 s0 = (f32x4){0.f, 0.f, 0.f, 0.f};
        f32x4 s1 = (f32x4){0.f, 0.f, 0.f, 0.f};
#pragma unroll
        for (int c = 0; c < 4; ++c) {
            const float* kp0 = Kb + ((size_t)(k0 + lo)) * KVD + c * 32 + g * 8;
            const float* kp1 = kp0 + (size_t)16 * KVD;
            float4 a0 = *(const float4*)(kp0);
            float4 a1 = *(const float4*)(kp0 + 4);
            float4 b0 = *(const float4*)(kp1);
            float4 b1 = *(const float4*)(kp1 + 4);
            bf16x8 kf0, kf1;
            kf0[0] = f2b(a0.x); kf0[1] = f2b(a0.y); kf0[2] = f2b(a0.z); kf0[3] = f2b(a0.w);
            kf0[4] = f2b(a1.x); kf0[5] = f2b(a1.y); kf0[6] = f2b(a1.z); kf0[7] = f2b(a1.w);
            kf1[0] = f2b(b0.x); kf1[1] = f2b(b0.y); kf1[2] = f2b(b0.z); kf1[3] = f2b(b0.w);
            kf1[4] = f2b(b1.x); kf1[5] = f2b(b1.y); kf1[6] = f2b(b1.z); kf1[7] = f2b(b1.w);
            s0 = __builtin_amdgcn_mfma_f32_16x16x32_bf16(qf[c], kf0, s0, 0, 0, 0);
            s1 = __builtin_amdgcn_mfma_f32_16x16x32_bf16(qf[c], kf1, s1, 0, 0, 0);
        }

        // ---- online softmax (wave-parallel, 16-lane butterfly per q-row) ----
        const bool needmask = (k0 + 31) > qw0;
#pragma unroll
        for (int i = 0; i < 4; ++i) {
            const int qi = qw0 + 4 * g + i;    // C-layout row
            float v0 = s0[i], v1 = s1[i];
            if (needmask) {
                if (k0 + lo > qi)      v0 = -INFINITY;
                if (k0 + 16 + lo > qi) v1 = -INFINITY;
            }
            float tm = fmaxf(v0, v1);
            tm = fmaxf(tm, __shfl_xor(tm, 1));
            tm = fmaxf(tm, __shfl_xor(tm, 2));
            tm = fmaxf(tm, __shfl_xor(tm, 4));
            tm = fmaxf(tm, __shfl_xor(tm, 8));
            const float mn = fmaxf(m_[i], tm);
            const float al = EXP2F((m_[i] - mn) * (SCALE_ * LOG2E_));
            m_[i] = mn;
            const float mc = mn * (SCALE_ * LOG2E_);
            const float p0 = EXP2F(v0 * (SCALE_ * LOG2E_) - mc);
            const float p1 = EXP2F(v1 * (SCALE_ * LOG2E_) - mc);
            float rs = p0 + p1;
            rs += __shfl_xor(rs, 1);
            rs += __shfl_xor(rs, 2);
            rs += __shfl_xor(rs, 4);
            rs += __shfl_xor(rs, 8);
            lsum[i] = lsum[i] * al + rs;
#pragma unroll
            for (int db = 0; db < 8; ++db) o_[db][i] *= al;
            PW[w][(4 * g + i) * PW_STR + lo]      = f2b(p0);
            PW[w][(4 * g + i) * PW_STR + 16 + lo] = f2b(p1);
        }

        // ---- PV: P via LDS round-trip (A-frag), V^T b128 reads (B-frag) ----
        bf16x8 pf = *(const bf16x8*)(&PW[w][lo * PW_STR + g * 8]);
#pragma unroll
        for (int db = 0; db < 8; ++db) {
            bf16x8 vf = *(const bf16x8*)(&VT[(db * 16 + lo) * VT_STR + g * 8]);
            o_[db] = __builtin_amdgcn_mfma_f32_16x16x32_bf16(pf, vf, o_[db], 0, 0, 0);
        }
    }

    // ---- epilogue: normalize and store f32 ----
#pragma unroll
    for (int i = 0; i < 4; ++i) {
        const float inv = 1.0f / lsum[i];
        float* op = O + ((size_t)(b * SEQ_ + qw0 + 4 * g + i)) * (H_ * DV_) + h * DV_ + lo;
#pragma unroll
        for (int db = 0; db < 8; ++db) op[db * 16] = o_[db][i] * inv;
    }
}

extern "C" void kernel_launch(void* const* d_in, const int* in_sizes, int n_in,
                              void* d_out, int out_size, void* d_ws, size_t ws_size,
                              hipStream_t stream) {
    const float* Q = (const float*)d_in[0];
    const float* K = (const float*)d_in[1];
    const float* V = (const float*)d_in[2];
    float* Out = (float*)d_out;
    // grid = B(4) * H(32) * qtiles(16) = 2048, block = 4 waves
    attn_fwd<<<dim3(2048), dim3(256), 0, stream>>>(Q, K, V, Out);
}

// Round 2
// 178.639 us; speedup vs baseline: 2.2280x; 2.2280x over previous
//
#include <hip/hip_runtime.h>
#include <hip/hip_bf16.h>

#define H_   32
#define KVH_ 8
#define D_   128
#define DV_  128
#define SEQ_ 1024
#define QKD  (H_*D_)     // 4096 floats per token row of Q
#define KVD  (KVH_*D_)   // 1024 floats per token row of K/V
#define SCALE_ 0.08838834764831845f
#define LOG2E_ 1.4426950408889634f

typedef __attribute__((ext_vector_type(8))) short bf16x8;
typedef __attribute__((ext_vector_type(4))) float f32x4;
typedef __attribute__((ext_vector_type(4))) unsigned int u32x4;

#if __has_builtin(__builtin_amdgcn_exp2f)
#define EXP2F(x) __builtin_amdgcn_exp2f(x)
#else
#define EXP2F(x) exp2f(x)
#endif

static __device__ __forceinline__ unsigned short f2b(float x) {
    __hip_bfloat16 b = __float2bfloat16(x);
    return __builtin_bit_cast(unsigned short, b);
}
static __device__ __forceinline__ unsigned pk2(float a, float b) {
    return (unsigned)f2b(a) | ((unsigned)f2b(b) << 16);
}

// K tile: [32 rows][128 halfs] linear 256B rows, XOR-swizzled byte^((row&7)<<4)
// V^T tile: [dv=128][stride 40 halfs] (32 k-cols used, +8 pad) -> 2-way free
// P per-wave: [q=16][stride 40 halfs]
#define VT_STR 40
#define PW_STR 40

__global__ __launch_bounds__(256, 4)
void attn_fwd(const float* __restrict__ Q, const float* __restrict__ K,
              const float* __restrict__ V, float* __restrict__ O) {
    __shared__ __align__(16) unsigned short KS[32 * 128];
    __shared__ __align__(16) unsigned short VT[DV_ * VT_STR];
    __shared__ __align__(16) unsigned short PW[4][16 * PW_STR];

    // grid = B(4) * H(32) * pair(8) = 1024; XCD-bijective swizzle (1024%8==0)
    const int bid = ((int)blockIdx.x & 7) * 128 + ((int)blockIdx.x >> 3);
    const int p   = bid & 7;           // pair index: q-tiles {p, 15-p} -> 34 k-tiles/block, uniform
    const int h   = (bid >> 3) & 31;   // query head
    const int b   = bid >> 8;          // batch
    const int kvh = h >> 2;            // GQA group of 4

    const int tid = threadIdx.x;
    const int w   = tid >> 6;          // wave 0..3
    const int l   = tid & 63;
    const int lo  = l & 15;
    const int g   = l >> 4;

    // staging thread mappings
    const int kr_ = tid >> 3;          // K stage row 0..31
    const int kq_ = tid & 7;           // K stage 16-float quarter
    const int sdv = tid & 127;         // V stage dv column
    const int skh = tid >> 7;          // V stage k-half (0/1)

    const float* Kb = K + ((size_t)(b * SEQ_)) * KVD + kvh * D_;
    const float* Vb = V + ((size_t)(b * SEQ_)) * KVD + kvh * DV_;

    float4 kpre[4];
    float  vpre[16];

    auto stage_load = [&](int t) {   // issue global loads for k-tile t -> regs
        const float* kp = Kb + ((size_t)(t * 32 + kr_)) * KVD + kq_ * 16;
        kpre[0] = *(const float4*)(kp);
        kpre[1] = *(const float4*)(kp + 4);
        kpre[2] = *(const float4*)(kp + 8);
        kpre[3] = *(const float4*)(kp + 12);
        const float* vp = Vb + ((size_t)(t * 32 + skh * 16)) * KVD + sdv;
#pragma unroll
        for (int e = 0; e < 16; ++e) vpre[e] = vp[(size_t)e * KVD];
    };
    auto stage_write = [&]() {       // cvt + LDS write of the prefetched tile
        const int kb0 = (kr_ * 256 + kq_ * 32) ^ ((kr_ & 7) << 4);
        const int kb1 = (kr_ * 256 + kq_ * 32 + 16) ^ ((kr_ & 7) << 4);
        u32x4 ka = { pk2(kpre[0].x, kpre[0].y), pk2(kpre[0].z, kpre[0].w),
                     pk2(kpre[1].x, kpre[1].y), pk2(kpre[1].z, kpre[1].w) };
        u32x4 kb = { pk2(kpre[2].x, kpre[2].y), pk2(kpre[2].z, kpre[2].w),
                     pk2(kpre[3].x, kpre[3].y), pk2(kpre[3].z, kpre[3].w) };
        *(u32x4*)((char*)KS + kb0) = ka;
        *(u32x4*)((char*)KS + kb1) = kb;
        u32x4 v0 = { pk2(vpre[0], vpre[1]),  pk2(vpre[2], vpre[3]),
                     pk2(vpre[4], vpre[5]),  pk2(vpre[6], vpre[7]) };
        u32x4 v1 = { pk2(vpre[8], vpre[9]),  pk2(vpre[10], vpre[11]),
                     pk2(vpre[12], vpre[13]), pk2(vpre[14], vpre[15]) };
        *(u32x4*)(&VT[sdv * VT_STR + skh * 16])     = v0;
        *(u32x4*)(&VT[sdv * VT_STR + skh * 16 + 8]) = v1;
    };

#pragma unroll 1
    for (int ph = 0; ph < 2; ++ph) {
        const int qt     = ph ? (15 - p) : p;
        const int ntiles = 2 * qt + 2;
        const int qw0    = qt * 64 + w * 16;
        const int jmaxw  = (qw0 + 15) >> 5;

        // Q fragments: row = lo, d = 32c + 8g + e
        const float* Qb = Q + ((size_t)(b * SEQ_ + qw0 + lo)) * QKD + h * D_;
        bf16x8 qf[4];
#pragma unroll
        for (int c = 0; c < 4; ++c) {
            const float* qp = Qb + c * 32 + g * 8;
            float4 x0 = *(const float4*)(qp);
            float4 x1 = *(const float4*)(qp + 4);
            bf16x8 f;
            f[0] = f2b(x0.x); f[1] = f2b(x0.y); f[2] = f2b(x0.z); f[3] = f2b(x0.w);
            f[4] = f2b(x1.x); f[5] = f2b(x1.y); f[6] = f2b(x1.z); f[7] = f2b(x1.w);
            qf[c] = f;
        }

        float m_[4], lsum[4];
        f32x4 o_[8];
#pragma unroll
        for (int i = 0; i < 4; ++i) { m_[i] = -INFINITY; lsum[i] = 0.f; }
#pragma unroll
        for (int db = 0; db < 8; ++db) o_[db] = (f32x4){0.f, 0.f, 0.f, 0.f};

        stage_load(0);

        for (int j = 0; j < ntiles; ++j) {
            __syncthreads();                       // prev tile's LDS readers done
            stage_write();
            __syncthreads();                       // tile visible to all waves
            if (j + 1 < ntiles) stage_load(j + 1); // issue next loads; they fly under compute
            if (j <= jmaxw) {
                const int k0 = j * 32;

                // ---- S = Q K^T ----
                f32x4 s0 = (f32x4){0.f, 0.f, 0.f, 0.f};
                f32x4 s1 = (f32x4){0.f, 0.f, 0.f, 0.f};
                const int sw = (lo & 7) << 4;
#pragma unroll
                for (int c = 0; c < 4; ++c) {
                    bf16x8 kf0 = *(const bf16x8*)((const char*)KS +
                                   ((lo * 256 + c * 64 + g * 16) ^ sw));
                    bf16x8 kf1 = *(const bf16x8*)((const char*)KS +
                                   (((16 + lo) * 256 + c * 64 + g * 16) ^ sw));
                    s0 = __builtin_amdgcn_mfma_f32_16x16x32_bf16(qf[c], kf0, s0, 0, 0, 0);
                    s1 = __builtin_amdgcn_mfma_f32_16x16x32_bf16(qf[c], kf1, s1, 0, 0, 0);
                }

                // ---- online softmax ----
                const bool needmask = (k0 + 31) > qw0;
#pragma unroll
                for (int i = 0; i < 4; ++i) {
                    const int qi = qw0 + 4 * g + i;
                    float v0 = s0[i], v1 = s1[i];
                    if (needmask) {
                        if (k0 + lo > qi)      v0 = -INFINITY;
                        if (k0 + 16 + lo > qi) v1 = -INFINITY;
                    }
                    float tm = fmaxf(v0, v1);
                    tm = fmaxf(tm, __shfl_xor(tm, 1));
                    tm = fmaxf(tm, __shfl_xor(tm, 2));
                    tm = fmaxf(tm, __shfl_xor(tm, 4));
                    tm = fmaxf(tm, __shfl_xor(tm, 8));
                    const float mn = fmaxf(m_[i], tm);
                    const float al = EXP2F((m_[i] - mn) * (SCALE_ * LOG2E_));
                    m_[i] = mn;
                    const float mc = mn * (SCALE_ * LOG2E_);
                    const float p0 = EXP2F(v0 * (SCALE_ * LOG2E_) - mc);
                    const float p1 = EXP2F(v1 * (SCALE_ * LOG2E_) - mc);
                    float rs = p0 + p1;
                    rs += __shfl_xor(rs, 1);
                    rs += __shfl_xor(rs, 2);
                    rs += __shfl_xor(rs, 4);
                    rs += __shfl_xor(rs, 8);
                    lsum[i] = lsum[i] * al + rs;
#pragma unroll
                    for (int db = 0; db < 8; ++db) o_[db][i] *= al;
                    PW[w][(4 * g + i) * PW_STR + lo]      = f2b(p0);
                    PW[w][(4 * g + i) * PW_STR + 16 + lo] = f2b(p1);
                }

                // ---- PV ----
                bf16x8 pf = *(const bf16x8*)(&PW[w][lo * PW_STR + g * 8]);
#pragma unroll
                for (int db = 0; db < 8; ++db) {
                    bf16x8 vf = *(const bf16x8*)(&VT[(db * 16 + lo) * VT_STR + g * 8]);
                    o_[db] = __builtin_amdgcn_mfma_f32_16x16x32_bf16(pf, vf, o_[db], 0, 0, 0);
                }
            }
        }

        // ---- epilogue ----
#pragma unroll
        for (int i = 0; i < 4; ++i) {
            const float inv = 1.0f / lsum[i];
            float* op = O + ((size_t)(b * SEQ_ + qw0 + 4 * g + i)) * (H_ * DV_) + h * DV_ + lo;
#pragma unroll
            for (int db = 0; db < 8; ++db) op[db * 16] = o_[db][i] * inv;
        }
    }
}

extern "C" void kernel_launch(void* const* d_in, const int* in_sizes, int n_in,
                              void* d_out, int out_size, void* d_ws, size_t ws_size,
                              hipStream_t stream) {
    const float* Q = (const float*)d_in[0];
    const float* K = (const float*)d_in[1];
    const float* V = (const float*)d_in[2];
    float* Out = (float*)d_out;
    // grid = B(4) * H(32) * 8 pairs = 1024 blocks of 4 waves, uniform work
    attn_fwd<<<dim3(1024), dim3(256), 0, stream>>>(Q, K, V, Out);
}